// Round 7
// baseline (155.202 us; speedup 1.0000x reference)
//
#include <hip/hip_runtime.h>

// Varlen GQA causal attention, v11: 8-wave paired-tile blocks + coarse split-K.
// Evidence (r2/r3/r6): all configs latency-bound at 16-20 resident waves/CU
// (occupancy 13-24%, Mfma/VALU/HBM all <20%); BM32-style staging amortization
// is work-efficient but split-256's combine overhead ate the gains.
// v11: block = 512 thr = 8 waves; waves 0-3 own q-tile q0, waves 4-7 own q0+16
// (two 16-row tiles share one K/V stage -> BM32 amortization with BM16 per-wave
// latency). LDS 36.9 KB -> 4 blocks/CU x 8 waves = 32 waves/CU (HW max).
// SPLIT=512 (<=8 iters/block, partials only for kend>512 tiles), MAXSPL=2.
// Per-wave inner loop is v5/v10-verbatim (proven); combine is v10-verbatim.
// S^T = K·(scaled Q)^T, O^T = V^T·P^T  (mfma_f32_16x16x32_bf16).

#define H      16
#define HKV    4
#define D      64
#define BM     16
#define BN     64
#define KSTR   72
#define PSTR   72
#define SPLIT  512        // keys per split-block = 8 iters of BN
#define MAXSPL 2          // ceil(max_seqlen/SPLIT); benchmark max_seqlen = 1024
#define NTMAX  64         // ceil(max_seqlen/BM) (16-row tiles)
#define PAIRX  64         // (max pairs per seq = 32) * MAXSPL
#define SLOTF  4160       // floats per partial slot: 4 heads*16 rows*64 d + 4*16 l
#define NEGF (-1e30f)

using bf8 = __attribute__((ext_vector_type(8))) short;
using f4v = __attribute__((ext_vector_type(4))) float;
typedef unsigned int u32;

union bf8u { bf8 v; u32 w[4]; };

// pack two fp32 -> [bf16(b)<<16 | bf16(a)], round-half-up (2 add + 1 perm)
__device__ inline u32 pk(float a, float b) {
    union { float f; u32 u; } x, y; x.f = a; y.f = b;
    return __builtin_amdgcn_perm(y.u + 0x8000u, x.u + 0x8000u, 0x07060302u);
}

// raw v_exp_f32 (exp2): masked lanes are -1e30 -> 0; live scores bounded
__device__ inline float fexp2(float x) {
    float r; asm("v_exp_f32 %0, %1" : "=v"(r) : "v"(x)); return r;
}

#define MFMA(A, B, C) __builtin_amdgcn_mfma_f32_16x16x32_bf16(A, B, C, 0, 0, 0)

// ---------- kernel A: preconvert ----------
__global__ __launch_bounds__(256)
void preconv(const float* __restrict__ kv, short* __restrict__ Kb,
             short* __restrict__ Vb, int total)
{
    const int tile = blockIdx.x, kvh = blockIdx.y, t = threadIdx.x;
    const int d4 = t & 15;
    #pragma unroll
    for (int i = 0; i < 4; ++i) {
        int tok = tile * 64 + (t >> 4) + 16 * i;
        if (tok < total) {
            float4 v = *(const float4*)&kv[(size_t)tok * 512 + kvh * 64 + d4 * 4];
            *(uint2*)&Kb[((size_t)kvh * total + tok) * 64 + d4 * 4] =
                make_uint2(pk(v.x, v.y), pk(v.z, v.w));
        }
    }
    #pragma unroll
    for (int i = 0; i < 2; ++i) {
        int ta = tile * 64 + 2 * ((t >> 4) + 16 * i);
        if (ta < total) {
            int tb = min(ta + 1, total - 1);
            float4 va = *(const float4*)&kv[(size_t)ta * 512 + (HKV + kvh) * 64 + d4 * 4];
            float4 vb = *(const float4*)&kv[(size_t)tb * 512 + (HKV + kvh) * 64 + d4 * 4];
            const float* pa = &va.x; const float* pb = &vb.x;
            #pragma unroll
            for (int j = 0; j < 4; ++j)
                *(u32*)&Vb[((size_t)kvh * 64 + 4 * d4 + j) * total + ta] = pk(pa[j], pb[j]);
        }
    }
}

// ---------- kernel B: attention (8 waves, paired tiles, split-K) ----------
__global__ __launch_bounds__(512, 8)
void attn11(const float* __restrict__ q, const short* __restrict__ Kb,
            const short* __restrict__ Vb, const int* __restrict__ cu,
            float* __restrict__ out, float* __restrict__ Pp, int total)
{
    __shared__ __attribute__((aligned(16))) short Ks[BN * KSTR];      // [key][d]
    __shared__ __attribute__((aligned(16))) short Vt[D * KSTR];       // [d][key]
    __shared__ __attribute__((aligned(16))) short Ps[8][BM * PSTR];   // per-wave [qrow][key]

    const int z = blockIdx.z, kvh = blockIdx.y;
    const int pair = blockIdx.x >> 1, split = blockIdx.x & 1;
    const int start = cu[z], len = cu[z + 1] - start;
    const int qb = pair * 32;
    if (qb >= len) return;
    const int kend = min(qb + 32, len);          // union kend (upper tile)
    const int nsb = (kend + SPLIT - 1) / SPLIT;
    if (split >= nsb) return;
    const int ks0 = split * SPLIT;
    const int ks1 = min(kend, ks0 + SPLIT);

    const int t = threadIdx.x, w = t >> 6, lane = t & 63;
    const int qd = lane >> 4, c = lane & 15;
    const int h = kvh * 4 + (w & 3);
    const int q0 = qb + 16 * (w >> 2);           // per-wave 16-row tile
    const int rows = min(BM, len - q0);          // <=0 if upper tile absent
    const int tg = (qb >> 4) + (w >> 2);         // per-seq 16-tile index
    const int nsw = (q0 + max(rows, 0) + SPLIT - 1) / SPLIT;  // wave's own nsplit
    const float SC = 0.125f * 1.44269504f;       // scale * log2(e)

    // ---- Q B-fragments straight from global (scaled) ----
    bf8u qf0, qf1;
    {
        int qr = max(min(c, rows - 1), 0);
        const float* qp = q + (size_t)(start + min(q0 + qr, len - 1)) * (H * D) + h * D + qd * 8;
        float4 a0 = *(const float4*)qp;
        float4 a1 = *(const float4*)(qp + 4);
        float4 a2 = *(const float4*)(qp + 32);
        float4 a3 = *(const float4*)(qp + 36);
        qf0.w[0] = pk(a0.x * SC, a0.y * SC); qf0.w[1] = pk(a0.z * SC, a0.w * SC);
        qf0.w[2] = pk(a1.x * SC, a1.y * SC); qf0.w[3] = pk(a1.z * SC, a1.w * SC);
        qf1.w[0] = pk(a2.x * SC, a2.y * SC); qf1.w[1] = pk(a2.z * SC, a2.w * SC);
        qf1.w[2] = pk(a3.x * SC, a3.y * SC); qf1.w[3] = pk(a3.z * SC, a3.w * SC);
    }

    // staging roles (512 thr): row sr (0..63), granule sg (0..7), 16B each
    const int sr = t >> 3, sg = t & 7;
    const short* Kbh = Kb + (size_t)kvh * total * 64;
    const short* Vbh = Vb + (size_t)kvh * 64 * total;
    uint4 kpre, vpre;

    auto prefetch = [&](int kt0) {
        int tok = min(start + kt0 + sr, total - 1);
        kpre = *(const uint4*)(Kbh + (size_t)tok * 64 + sg * 8);
        int t0 = min(start + kt0 + 8 * sg, total - 8);       // clamp: OOB keys masked
        vpre = *(const uint4*)(Vbh + (size_t)sr * total + t0);
    };

    float l_i = 0.f;
    f4v o0 = {0,0,0,0}, o1 = {0,0,0,0}, o2 = {0,0,0,0}, o3 = {0,0,0,0};
    short* Psw = &Ps[w][0];

    prefetch(ks0);

    for (int kt0 = ks0; kt0 < ks1; kt0 += BN) {
        __syncthreads();                         // prev-iter LDS readers done
        *(uint4*)&Ks[sr * KSTR + sg * 8] = kpre;
        *(uint4*)&Vt[sr * KSTR + sg * 8] = vpre;
        __syncthreads();

        if (kt0 + BN < ks1) prefetch(kt0 + BN);  // overlaps compute below

        // ---- S^T: 4 key-tiles of 16 ----
        f4v s0 = {0,0,0,0}, s1 = {0,0,0,0}, s2 = {0,0,0,0}, s3 = {0,0,0,0};
        {
            bf8 ka, kb;
            ka = *(const bf8*)&Ks[(c     ) * KSTR + qd * 8];
            kb = *(const bf8*)&Ks[(c     ) * KSTR + 32 + qd * 8];
            s0 = MFMA(ka, qf0.v, s0); s0 = MFMA(kb, qf1.v, s0);
            ka = *(const bf8*)&Ks[(16 + c) * KSTR + qd * 8];
            kb = *(const bf8*)&Ks[(16 + c) * KSTR + 32 + qd * 8];
            s1 = MFMA(ka, qf0.v, s1); s1 = MFMA(kb, qf1.v, s1);
            ka = *(const bf8*)&Ks[(32 + c) * KSTR + qd * 8];
            kb = *(const bf8*)&Ks[(32 + c) * KSTR + 32 + qd * 8];
            s2 = MFMA(ka, qf0.v, s2); s2 = MFMA(kb, qf1.v, s2);
            ka = *(const bf8*)&Ks[(48 + c) * KSTR + qd * 8];
            kb = *(const bf8*)&Ks[(48 + c) * KSTR + 32 + qd * 8];
            s3 = MFMA(ka, qf0.v, s3); s3 = MFMA(kb, qf1.v, s3);
        }

        // ---- no-max softmax: e = exp2(s), masked -> 0; l accumulates per-lane ----
        float e[16];
        #pragma unroll
        for (int r = 0; r < 4; ++r) {
            e[r] = s0[r]; e[4 + r] = s1[r]; e[8 + r] = s2[r]; e[12 + r] = s3[r];
        }
        if (kt0 + 63 > q0) {                     // only iters touching this wave's diagonal
            const int limit = q0 + c - kt0;
            #pragma unroll
            for (int j = 0; j < 4; ++j)
                #pragma unroll
                for (int r = 0; r < 4; ++r)
                    if (16 * j + 4 * qd + r > limit) e[4 * j + r] = NEGF;
        }
        float ls = 0.f;
        #pragma unroll
        for (int i = 0; i < 16; ++i) { e[i] = fexp2(e[i]); ls += e[i]; }
        l_i += ls;

        // ---- P -> wave-private LDS [qrow][key] (no barrier), read fragments ----
        #pragma unroll
        for (int j = 0; j < 4; ++j) {
            u32 lo = pk(e[4 * j], e[4 * j + 1]), hi = pk(e[4 * j + 2], e[4 * j + 3]);
            *(uint2*)&Psw[c * PSTR + 16 * j + 4 * qd] = make_uint2(lo, hi);
        }
        bf8 p0 = *(const bf8*)&Psw[c * PSTR + qd * 8];
        bf8 p1 = *(const bf8*)&Psw[c * PSTR + 32 + qd * 8];

        // ---- O^T += V^T · P^T ----
        o0 = MFMA(*(const bf8*)&Vt[(c     ) * KSTR + qd * 8],      p0, o0);
        o0 = MFMA(*(const bf8*)&Vt[(c     ) * KSTR + 32 + qd * 8], p1, o0);
        o1 = MFMA(*(const bf8*)&Vt[(16 + c) * KSTR + qd * 8],      p0, o1);
        o1 = MFMA(*(const bf8*)&Vt[(16 + c) * KSTR + 32 + qd * 8], p1, o1);
        o2 = MFMA(*(const bf8*)&Vt[(32 + c) * KSTR + qd * 8],      p0, o2);
        o2 = MFMA(*(const bf8*)&Vt[(32 + c) * KSTR + 32 + qd * 8], p1, o2);
        o3 = MFMA(*(const bf8*)&Vt[(48 + c) * KSTR + qd * 8],      p0, o3);
        o3 = MFMA(*(const bf8*)&Vt[(48 + c) * KSTR + 32 + qd * 8], p1, o3);
    }

    // ---- epilogue: cross-lane l reduction (quads hold disjoint key partials) ----
    float lt = l_i + __shfl_xor(l_i, 16, 64);
    lt += __shfl_xor(lt, 32, 64);
    if (rows > 0 && c < rows) {
        if (nsw == 1) {
            if (split == 0) {                    // wave's whole key range is in split 0
                const float inv = 1.f / lt;
                float* op = out + (size_t)(start + q0 + c) * (H * D) + h * D + 4 * qd;
                *(float4*)(op)      = make_float4(o0[0] * inv, o0[1] * inv, o0[2] * inv, o0[3] * inv);
                *(float4*)(op + 16) = make_float4(o1[0] * inv, o1[1] * inv, o1[2] * inv, o1[3] * inv);
                *(float4*)(op + 32) = make_float4(o2[0] * inv, o2[1] * inv, o2[2] * inv, o2[3] * inv);
                *(float4*)(op + 48) = make_float4(o3[0] * inv, o3[1] * inv, o3[2] * inv, o3[3] * inv);
            }
        } else {
            float* sp = Pp + (size_t)(((z * NTMAX + tg) * HKV + kvh) * MAXSPL + split) * SLOTF;
            float* op = sp + (w & 3) * 1024 + c * 64 + 4 * qd;
            *(float4*)(op)      = make_float4(o0[0], o0[1], o0[2], o0[3]);
            *(float4*)(op + 16) = make_float4(o1[0], o1[1], o1[2], o1[3]);
            *(float4*)(op + 32) = make_float4(o2[0], o2[1], o2[2], o2[3]);
            *(float4*)(op + 48) = make_float4(o3[0], o3[1], o3[2], o3[3]);
            if (qd == 0) sp[4096 + (w & 3) * 16 + c] = lt;
        }
    }
}

// ---------- kernel C: combine split partials + normalize ----------
__global__ __launch_bounds__(256)
void combine(const int* __restrict__ cu, const float* __restrict__ Pp,
             float* __restrict__ out)
{
    const int z = blockIdx.z, kvh = blockIdx.y, tile = blockIdx.x;
    const int start = cu[z], len = cu[z + 1] - start;
    const int q0 = tile * BM;
    if (q0 >= len) return;
    const int rows = min(BM, len - q0);
    const int nsplit = (q0 + rows + SPLIT - 1) / SPLIT;
    if (nsplit < 2) return;                       // attn wrote out directly

    const int t = threadIdx.x, w = t >> 6, tt = t & 63;
    const int row = tt >> 2, col0 = (tt & 3) * 16;
    if (row >= rows) return;

    const float* slot0 = Pp + (size_t)(((z * NTMAX + tile) * HKV + kvh) * MAXSPL) * SLOTF;
    float o[16];
    #pragma unroll
    for (int u = 0; u < 16; ++u) o[u] = 0.f;
    float lsum = 0.f;
    for (int s = 0; s < nsplit; ++s) {
        const float* sp = slot0 + (size_t)s * SLOTF;
        lsum += sp[4096 + w * 16 + row];
        const float* op = sp + w * 1024 + row * 64 + col0;
        #pragma unroll
        for (int u = 0; u < 4; ++u) {
            float4 v = *(const float4*)(op + 4 * u);
            o[4 * u]     += v.x; o[4 * u + 1] += v.y;
            o[4 * u + 2] += v.z; o[4 * u + 3] += v.w;
        }
    }
    const float inv = 1.f / lsum;
    float* dst = out + (size_t)(start + q0 + row) * (H * D) + (kvh * 4 + w) * 64 + col0;
    #pragma unroll
    for (int u = 0; u < 4; ++u)
        *(float4*)(dst + 4 * u) = make_float4(o[4 * u] * inv, o[4 * u + 1] * inv,
                                              o[4 * u + 2] * inv, o[4 * u + 3] * inv);
}

extern "C" void kernel_launch(void* const* d_in, const int* in_sizes, int n_in,
                              void* d_out, int out_size, void* d_ws, size_t ws_size,
                              hipStream_t stream) {
    const float* q  = (const float*)d_in[0];
    const float* kv = (const float*)d_in[1];
    const int*   cu = (const int*)d_in[2];
    float* out = (float*)d_out;

    const int total = in_sizes[0] / (H * D);
    const int nb    = in_sizes[2] - 1;

    short* Kb = (short*)d_ws;                               // 4*total*64 bf16
    short* Vb = Kb + (size_t)HKV * total * 64;              // 4*total*64 bf16
    float* Pp = (float*)(Vb + (size_t)HKV * total * 64);    // partial slots (~68 MB)

    dim3 gridA((total + 63) / 64, HKV);
    preconv<<<gridA, 256, 0, stream>>>(kv, Kb, Vb, total);

    dim3 gridB(PAIRX, HKV, nb);                             // (pair,split) closed-form map
    attn11<<<gridB, 512, 0, stream>>>(q, Kb, Vb, cu, out, Pp, total);

    dim3 gridC(NTMAX, HKV, nb);
    combine<<<gridC, 256, 0, stream>>>(cu, Pp, out);
}

// Round 8
// 114.459 us; speedup vs baseline: 1.3560x; 1.3560x over previous
//
#include <hip/hip_runtime.h>

// Varlen GQA causal attention, v12 = v5 attn (verbatim, best measured) +
// coalesced preconv.
// Ledger across r0-r7: total - attn - combine = ~77 us CONSTANT. preconv's
// V^T path (8 scattered 4B stores/thread, stride total*4B, 352 blocks) was
// the hidden cost all along; every attn restructure (BM32/splitK/8-wave)
// regressed vs v5's 39 us. v12 reverts attn to v5 and fixes preconv:
// V transpose via padded LDS tile (Vp[64][33] u32, 2-way bank alias = free),
// writes go out 32B contiguous/lane (128B per 4 lanes) along tokens.
// Kernel A: kv fp32 -> bf16  Kb[kvh][tok][d], Vb[kvh][d][tok] (in d_ws).
// Kernel B: v5 verbatim. S^T = K·(scaled Q)^T, O^T = V^T·P^T.

#define H    16
#define HKV  4
#define D    64
#define BM   16
#define BN   64
#define KSTR 72
#define NEGF (-1e30f)

using bf8 = __attribute__((ext_vector_type(8))) short;
using f4v = __attribute__((ext_vector_type(4))) float;
typedef unsigned int u32;

union bf8u { bf8 v; u32 w[4]; };

// pack two fp32 -> [bf16(b)<<16 | bf16(a)], round-half-up (2 add + 1 perm)
__device__ inline u32 pk(float a, float b) {
    union { float f; u32 u; } x, y; x.f = a; y.f = b;
    return __builtin_amdgcn_perm(y.u + 0x8000u, x.u + 0x8000u, 0x07060302u);
}

#define MFMA(A, B, C) __builtin_amdgcn_mfma_f32_16x16x32_bf16(A, B, C, 0, 0, 0)

// ---------- kernel A: preconvert (coalesced V^T via LDS transpose) ----------
__global__ __launch_bounds__(256)
void preconv(const float* __restrict__ kv, short* __restrict__ Kb,
             short* __restrict__ Vb, int total)
{
    __shared__ u32 Vp[64 * 33];                  // [d][token-pair], stride 33 (pad)

    const int tile = blockIdx.x, kvh = blockIdx.y, t = threadIdx.x;
    const int d4 = t & 15;
    const int T0 = tile * 64;

    // K: [kvh][tok][d], coalesced in and out (unchanged, proven)
    #pragma unroll
    for (int i = 0; i < 4; ++i) {
        int tok = T0 + (t >> 4) + 16 * i;
        if (tok < total) {
            float4 v = *(const float4*)&kv[(size_t)tok * 512 + kvh * 64 + d4 * 4];
            *(uint2*)&Kb[((size_t)kvh * total + tok) * 64 + d4 * 4] =
                make_uint2(pk(v.x, v.y), pk(v.z, v.w));
        }
    }

    if (T0 + 64 <= total) {
        // ---- fast path: pack token-pairs into LDS, write out coalesced ----
        #pragma unroll
        for (int i = 0; i < 2; ++i) {
            int tp = (t >> 4) + 16 * i;          // token pair 0..31
            int ta = T0 + 2 * tp;
            float4 va = *(const float4*)&kv[(size_t)ta * 512 + (HKV + kvh) * 64 + d4 * 4];
            float4 vb = *(const float4*)&kv[(size_t)(ta + 1) * 512 + (HKV + kvh) * 64 + d4 * 4];
            const float* pa = &va.x; const float* pb = &vb.x;
            #pragma unroll
            for (int j = 0; j < 4; ++j)
                Vp[(4 * d4 + j) * 33 + tp] = pk(pa[j], pb[j]);
        }
        __syncthreads();
        // write out: row d, 8 u32 (16 tokens) per thread, 32B contiguous
        const int d = t >> 2, qq = t & 3;
        u32* dst = (u32*)Vb + ((size_t)kvh * 64 + d) * (total / 2) + T0 / 2 + 8 * qq;
        const u32* src = &Vp[d * 33 + 8 * qq];
        *(uint4*)(dst)     = *(const uint4*)(src);
        *(uint4*)(dst + 4) = *(const uint4*)(src + 4);
    } else {
        // ---- tail tile: original (scattered) path, guarded ----
        #pragma unroll
        for (int i = 0; i < 2; ++i) {
            int ta = T0 + 2 * ((t >> 4) + 16 * i);
            if (ta < total) {
                int tb = min(ta + 1, total - 1);
                float4 va = *(const float4*)&kv[(size_t)ta * 512 + (HKV + kvh) * 64 + d4 * 4];
                float4 vb = *(const float4*)&kv[(size_t)tb * 512 + (HKV + kvh) * 64 + d4 * 4];
                const float* pa = &va.x; const float* pb = &vb.x;
                #pragma unroll
                for (int j = 0; j < 4; ++j)
                    *(u32*)&Vb[((size_t)kvh * 64 + 4 * d4 + j) * total + ta] = pk(pa[j], pb[j]);
            }
        }
    }
}

// ---------- kernel B: attention (v5 verbatim) ----------
__global__ __launch_bounds__(256, 5)
void attn5(const float* __restrict__ q, const short* __restrict__ Kb,
           const short* __restrict__ Vb, const int* __restrict__ cu,
           float* __restrict__ out, int nb, int total)
{
    __shared__ __attribute__((aligned(16))) short Ks[BN * KSTR];      // [key][d]
    __shared__ __attribute__((aligned(16))) short Vt[D * KSTR];       // [d][key]
    __shared__ __attribute__((aligned(16))) short Ps[4][BM * KSTR];   // per-wave [qrow][key]

    const int kvh = blockIdx.y;

    // locate (seq, q-tile); long tiles (high q0) first
    int bid = blockIdx.x, b = -1, start = 0, len = 0, q0 = 0, acc = 0;
    for (int i = 0; i < nb; ++i) {
        int s0 = cu[i], l = cu[i + 1] - s0, nt = (l + BM - 1) / BM;
        if (bid < acc + nt) { b = i; start = s0; len = l; q0 = (nt - 1 - (bid - acc)) * BM; break; }
        acc += nt;
    }
    if (b < 0) return;

    const int t = threadIdx.x, w = t >> 6, lane = t & 63;
    const int qd = lane >> 4, c = lane & 15;
    const int h = kvh * 4 + w;
    const int rows = min(BM, len - q0), kend = q0 + rows;
    const float SC = 0.125f * 1.44269504f;        // scale * log2(e)

    // ---- Q B-fragments straight from global (scaled) ----
    bf8u qf0, qf1;
    {
        int qr = min(c, rows - 1);
        const float* qp = q + (size_t)(start + q0 + qr) * (H * D) + h * D + qd * 8;
        float4 a0 = *(const float4*)qp;
        float4 a1 = *(const float4*)(qp + 4);
        float4 a2 = *(const float4*)(qp + 32);
        float4 a3 = *(const float4*)(qp + 36);
        qf0.w[0] = pk(a0.x * SC, a0.y * SC); qf0.w[1] = pk(a0.z * SC, a0.w * SC);
        qf0.w[2] = pk(a1.x * SC, a1.y * SC); qf0.w[3] = pk(a1.z * SC, a1.w * SC);
        qf1.w[0] = pk(a2.x * SC, a2.y * SC); qf1.w[1] = pk(a2.z * SC, a2.w * SC);
        qf1.w[2] = pk(a3.x * SC, a3.y * SC); qf1.w[3] = pk(a3.z * SC, a3.w * SC);
    }

    // staging roles: row sr (0..63), granules sg and sg+4 (8 bf16 = 16B each)
    const int sr = t >> 2, sg = t & 3;
    const short* Kbh = Kb + (size_t)kvh * total * 64;
    const short* Vbh = Vb + (size_t)kvh * 64 * total;
    uint4 kpre0, kpre1, vpre0, vpre1;

    auto prefetch = [&](int kt0) {
        int tok = min(start + kt0 + sr, total - 1);
        const short* kp = Kbh + (size_t)tok * 64 + sg * 8;
        kpre0 = *(const uint4*)(kp);
        kpre1 = *(const uint4*)(kp + 32);
        const short* vp = Vbh + (size_t)sr * total;
        int t0 = min(start + kt0 + 8 * sg, total - 8);       // clamp: OOB keys masked
        int t1 = min(start + kt0 + 8 * sg + 32, total - 8);
        vpre0 = *(const uint4*)(vp + t0);
        vpre1 = *(const uint4*)(vp + t1);
    };

    float l_i = 0.f;
    f4v o0 = {0,0,0,0}, o1 = {0,0,0,0}, o2 = {0,0,0,0}, o3 = {0,0,0,0};
    short* Psw = &Ps[w][0];

    prefetch(0);

    for (int kt0 = 0; kt0 < kend; kt0 += BN) {
        __syncthreads();                         // prev-iter LDS readers done
        *(uint4*)&Ks[sr * KSTR + sg * 8]      = kpre0;
        *(uint4*)&Ks[sr * KSTR + sg * 8 + 32] = kpre1;
        *(uint4*)&Vt[sr * KSTR + sg * 8]      = vpre0;
        *(uint4*)&Vt[sr * KSTR + sg * 8 + 32] = vpre1;
        __syncthreads();

        if (kt0 + BN < kend) prefetch(kt0 + BN); // overlaps compute below

        // ---- S^T: 4 key-tiles of 16 ----
        f4v s0 = {0,0,0,0}, s1 = {0,0,0,0}, s2 = {0,0,0,0}, s3 = {0,0,0,0};
        {
            bf8 ka, kb;
            ka = *(const bf8*)&Ks[(c     ) * KSTR + qd * 8];
            kb = *(const bf8*)&Ks[(c     ) * KSTR + 32 + qd * 8];
            s0 = MFMA(ka, qf0.v, s0); s0 = MFMA(kb, qf1.v, s0);
            ka = *(const bf8*)&Ks[(16 + c) * KSTR + qd * 8];
            kb = *(const bf8*)&Ks[(16 + c) * KSTR + 32 + qd * 8];
            s1 = MFMA(ka, qf0.v, s1); s1 = MFMA(kb, qf1.v, s1);
            ka = *(const bf8*)&Ks[(32 + c) * KSTR + qd * 8];
            kb = *(const bf8*)&Ks[(32 + c) * KSTR + 32 + qd * 8];
            s2 = MFMA(ka, qf0.v, s2); s2 = MFMA(kb, qf1.v, s2);
            ka = *(const bf8*)&Ks[(48 + c) * KSTR + qd * 8];
            kb = *(const bf8*)&Ks[(48 + c) * KSTR + 32 + qd * 8];
            s3 = MFMA(ka, qf0.v, s3); s3 = MFMA(kb, qf1.v, s3);
        }

        // ---- no-max softmax: e = exp2(s), masked -> 0; l accumulates per-lane ----
        float e[16];
        #pragma unroll
        for (int r = 0; r < 4; ++r) {
            e[r] = s0[r]; e[4 + r] = s1[r]; e[8 + r] = s2[r]; e[12 + r] = s3[r];
        }
        if (kt0 + 63 > q0) {                     // only tiles touching the diagonal
            const int limit = q0 + c - kt0;
            #pragma unroll
            for (int j = 0; j < 4; ++j)
                #pragma unroll
                for (int r = 0; r < 4; ++r)
                    if (16 * j + 4 * qd + r > limit) e[4 * j + r] = NEGF;
        }
        float ls = 0.f;
        #pragma unroll
        for (int i = 0; i < 16; ++i) { e[i] = exp2f(e[i]); ls += e[i]; }
        l_i += ls;

        // ---- P -> wave-private LDS [qrow][key] (no barrier), read fragments ----
        #pragma unroll
        for (int j = 0; j < 4; ++j) {
            u32 lo = pk(e[4 * j], e[4 * j + 1]), hi = pk(e[4 * j + 2], e[4 * j + 3]);
            *(uint2*)&Psw[c * KSTR + 16 * j + 4 * qd] = make_uint2(lo, hi);
        }
        bf8 p0 = *(const bf8*)&Psw[c * KSTR + qd * 8];
        bf8 p1 = *(const bf8*)&Psw[c * KSTR + 32 + qd * 8];

        // ---- O^T += V^T · P^T ----
        o0 = MFMA(*(const bf8*)&Vt[(c     ) * KSTR + qd * 8],      p0, o0);
        o0 = MFMA(*(const bf8*)&Vt[(c     ) * KSTR + 32 + qd * 8], p1, o0);
        o1 = MFMA(*(const bf8*)&Vt[(16 + c) * KSTR + qd * 8],      p0, o1);
        o1 = MFMA(*(const bf8*)&Vt[(16 + c) * KSTR + 32 + qd * 8], p1, o1);
        o2 = MFMA(*(const bf8*)&Vt[(32 + c) * KSTR + qd * 8],      p0, o2);
        o2 = MFMA(*(const bf8*)&Vt[(32 + c) * KSTR + 32 + qd * 8], p1, o2);
        o3 = MFMA(*(const bf8*)&Vt[(48 + c) * KSTR + qd * 8],      p0, o3);
        o3 = MFMA(*(const bf8*)&Vt[(48 + c) * KSTR + 32 + qd * 8], p1, o3);
    }

    // ---- epilogue: cross-lane l reduction (quads hold disjoint key partials) ----
    if (c < rows) {
        float lt = l_i + __shfl_xor(l_i, 16, 64);
        lt += __shfl_xor(lt, 32, 64);
        const float inv = 1.f / lt;
        float* op = out + (size_t)(start + q0 + c) * (H * D) + h * D + 4 * qd;
        *(float4*)(op)      = make_float4(o0[0] * inv, o0[1] * inv, o0[2] * inv, o0[3] * inv);
        *(float4*)(op + 16) = make_float4(o1[0] * inv, o1[1] * inv, o1[2] * inv, o1[3] * inv);
        *(float4*)(op + 32) = make_float4(o2[0] * inv, o2[1] * inv, o2[2] * inv, o2[3] * inv);
        *(float4*)(op + 48) = make_float4(o3[0] * inv, o3[1] * inv, o3[2] * inv, o3[3] * inv);
    }
}

extern "C" void kernel_launch(void* const* d_in, const int* in_sizes, int n_in,
                              void* d_out, int out_size, void* d_ws, size_t ws_size,
                              hipStream_t stream) {
    const float* q  = (const float*)d_in[0];
    const float* kv = (const float*)d_in[1];
    const int*   cu = (const int*)d_in[2];
    float* out = (float*)d_out;

    const int total = in_sizes[0] / (H * D);
    const int nb    = in_sizes[2] - 1;

    short* Kb = (short*)d_ws;                               // 4*total*64 bf16
    short* Vb = Kb + (size_t)HKV * total * 64;              // 4*total*64 bf16

    dim3 gridA((total + 63) / 64, HKV);
    preconv<<<gridA, 256, 0, stream>>>(kv, Kb, Vb, total);

    const int tile_ub = total / BM + nb;                    // >= sum of ceil(len/BM)
    dim3 gridB(tile_ub, HKV);
    attn5<<<gridB, 256, 0, stream>>>(q, Kb, Vb, cu, out, nb, total);
}